// Round 11
// baseline (296.786 us; speedup 1.0000x reference)
//
#include <hip/hip_runtime.h>
#include <hip/hip_bf16.h>

#define DI __device__ __forceinline__

typedef __bf16 bf16x8 __attribute__((ext_vector_type(8)));
typedef float  f32x4  __attribute__((ext_vector_type(4)));

DI unsigned short f2bf(float f) {
    unsigned int u = __float_as_uint(f);
    u += 0x7fffu + ((u >> 16) & 1u);
    return (unsigned short)(u >> 16);
}

DI void gload16(const unsigned short* g, unsigned short* l) {
    __builtin_amdgcn_global_load_lds(
        (const __attribute__((address_space(1))) unsigned int*)g,
        (__attribute__((address_space(3))) unsigned int*)l, 16, 0, 0);
}

// ---------------------------------------------------------------------------
__global__ void convert_x(const float* __restrict__ x, unsigned short* __restrict__ Xb) {
    int i = blockIdx.x * 256 + threadIdx.x;
    float4 v = reinterpret_cast<const float4*>(x)[i];
    ushort4 o;
    o.x = f2bf(v.x); o.y = f2bf(v.y); o.z = f2bf(v.z); o.w = f2bf(v.w);
    reinterpret_cast<ushort4*>(Xb)[i] = o;
}

__global__ void convert_w(const float* __restrict__ Wq, const float* __restrict__ Wk,
                          const float* __restrict__ Wv, unsigned short* __restrict__ Wt) {
    __shared__ float t[32][33];
    const int z = blockIdx.z;
    const float* W = (z == 0) ? Wq : (z == 1 ? Wk : Wv);
    const float scale = (z == 0) ? 0.03125f : 1.0f;
    const int n0 = blockIdx.x * 32, k0 = blockIdx.y * 32;
    const int tx = threadIdx.x, ty = threadIdx.y;
#pragma unroll
    for (int i = 0; i < 4; ++i)
        t[ty + i * 8][tx] = W[(size_t)(k0 + ty + i * 8) * 1024 + n0 + tx];
    __syncthreads();
#pragma unroll
    for (int i = 0; i < 4; ++i)
        Wt[(size_t)(z * 1024 + n0 + ty + i * 8) * 1024 + k0 + tx] =
            f2bf(t[tx][ty + i * 8] * scale);
}

#define BAR    asm volatile("s_barrier" ::: "memory")
#define WAITV3 asm volatile("s_waitcnt vmcnt(3)" ::: "memory")
#define WAITV0 asm volatile("s_waitcnt vmcnt(0)" ::: "memory")
#define LGKM0  asm volatile("s_waitcnt lgkmcnt(0)" ::: "memory")
#define SCHB   __builtin_amdgcn_sched_barrier(0)

// ---------------------------------------------------------------------------
// gemm256 ROUND 11 (= round 9 structure, VGPR-trimmed): full fragment
// double-buffer so the 96-read LDS burst for kt+1 drains under the FULL
// 1241-cyc MFMA cluster of kt (round 10's half-sweep gave it only 620cy ->
// ~500cy LGKM0 stall/kt). BK=32, 3 LDS slots (96 KiB), launch_bounds(512,2)
// -> 256-reg budget: acc 128 + frag dbuf 96 + ~20 addressing = ~244.
// Offset compression: swizzle term lg^((lr>>1)&3) is fragment-invariant
// (proof: r = R0 + (i&3)*16 + (i>>2)*128 -> (r>>1)&3 == (lr>>1)&3 since all
// deltas are 0 mod 8), so frag addrs = base + (i&3)*512 + (i>>2)*4096 with
// compile-time immediates.
// Per body(kt):
//   WAITV0  - drain stage(kt+1), issued 1 kt (~1400cy > 900cy HBM) earlier
//   LGKM0   - reads issued at body(kt-1) complete (had full MMA(kt-1) cover)
//   BAR     - collectivize both
//   stage(kt+2) -> slot(kt-1)  [WAR certified by LGKM0+BAR chain]
//   read ALL 12 frags(kt+1) from slot(kt+1)%3
//   SCHB; 32 MFMA on frags(kt) - zero lgkm dependence
// ---------------------------------------------------------------------------

#define G_STAGE(KT, SL)                                                       \
    {                                                                         \
        const unsigned kto_ = (unsigned)(KT) * 32u;                           \
        gload16(A0g + kto_ + sAg[0], lds + (SL) * 16384 + tid * 8);           \
        gload16(A0g + kto_ + sAg[1], lds + (SL) * 16384 + 4096 + tid * 8);    \
        gload16(B0g + kto_ + sBg[0], lds + (SL) * 16384 + 8192 + tid * 8);    \
        gload16(B0g + kto_ + sBg[1], lds + (SL) * 16384 + 12288 + tid * 8);   \
    }

#define G_READ(AV, BV, SL)                                                    \
    {                                                                         \
        const unsigned short* sp_ = lds + (SL) * 16384;                       \
        _Pragma("unroll")                                                     \
        for (int i_ = 0; i_ < 8; ++i_)                                        \
            AV[i_] = *reinterpret_cast<const bf16x8*>(                        \
                sp_ + abase + (i_ & 3) * 512 + (i_ >> 2) * 4096);             \
        _Pragma("unroll")                                                     \
        for (int j_ = 0; j_ < 4; ++j_)                                        \
            BV[j_] = *reinterpret_cast<const bf16x8*>(                        \
                sp_ + bbase + (j_ & 1) * 512 + (j_ >> 1) * 4096);             \
    }

#define G_MMA(AV, BV)                                                         \
    __builtin_amdgcn_s_setprio(1);                                            \
    _Pragma("unroll")                                                         \
    for (int i_ = 0; i_ < 8; ++i_)                                            \
        _Pragma("unroll")                                                     \
        for (int j_ = 0; j_ < 4; ++j_)                                        \
            acc[i_][j_] = __builtin_amdgcn_mfma_f32_16x16x32_bf16(            \
                AV[i_], BV[j_], acc[i_][j_], 0, 0, 0);                        \
    __builtin_amdgcn_s_setprio(0);

#define G_BODY(KT, AC, BC, AN, BN)                                            \
    {                                                                         \
        WAITV0; LGKM0; BAR;                                                   \
        if ((KT) + 2 < NT) { G_STAGE((KT) + 2, ((KT) + 2) % 3); }             \
        if ((KT) + 1 < NT) { G_READ(AN, BN, ((KT) + 1) % 3); }                \
        SCHB;                                                                 \
        G_MMA(AC, BC);                                                        \
    }

__global__ __launch_bounds__(512, 2) void gemm256(
    const unsigned short* __restrict__ A0g, const unsigned short* __restrict__ B0g,
    unsigned short* __restrict__ Oq, unsigned short* __restrict__ Ok,
    unsigned short* __restrict__ Ov)
{
    extern __shared__ unsigned short lds[];     // 3 slots x (A 8192 + B 8192) elems

    const int tid = threadIdx.x;
    const int lane = tid & 63;
    const int wid = tid >> 6;
    const int wm = wid >> 2, wn = wid & 3;
    const int lr = lane & 15, lg = lane >> 4;

    const int m0 = blockIdx.x * 256, n0 = blockIdx.y * 256;
    const int NT = 32;

    // stage source offsets (swizzle: chunk ^= (row>>1)&3; inverse on read)
    unsigned sAg[2], sBg[2];
#pragma unroll
    for (int it = 0; it < 2; ++it) {
        const unsigned idx = it * 512 + tid;
        const unsigned row = idx >> 2;
        const unsigned ch = (idx & 3u) ^ ((row >> 1) & 3u);
        sAg[it] = (unsigned)(m0 + row) * 1024u + ch * 8u;
        sBg[it] = (unsigned)(n0 + row) * 1024u + ch * 8u;
    }
    // fragment read bases (elements); per-fragment deltas are immediates
    const unsigned swz = ((unsigned)lg ^ (((unsigned)lr >> 1) & 3u)) << 3;
    const unsigned abase = (unsigned)(wm * 64 + lr) * 32u + swz;
    const unsigned bbase = 8192u + (unsigned)(wn * 32 + lr) * 32u + swz;

    f32x4 acc[8][4] = {};
    bf16x8 Aa[8], Ba[4], Ab2[8], Bb2[4];

    G_STAGE(0, 0); G_STAGE(1, 1);
    WAITV0; BAR;
    G_READ(Aa, Ba, 0);

    for (int kt = 0; kt < NT; kt += 2) {
        G_BODY(kt, Aa, Ba, Ab2, Bb2);
        G_BODY(kt + 1, Ab2, Bb2, Aa, Ba);
    }

    // epilogue: D frag layout col=lr, row=lg*4+r2
#pragma unroll
    for (int i = 0; i < 8; ++i) {
        const int rl = (i >> 2) * 128 + wm * 64 + (i & 3) * 16 + lg * 4;
#pragma unroll
        for (int j = 0; j < 4; ++j) {
            const int cl = (j >> 1) * 128 + wn * 32 + (j & 1) * 16 + lr;
            f32x4 v = acc[i][j];
            const int gm = m0 + rl;
            const int z = n0 >> 10;
            const int cin = (n0 & 1023) + cl;
            if (z == 2) {
                const int b = gm >> 11, nib = gm & 2047;
                ushort4 h;
                h.x = f2bf(v[0]); h.y = f2bf(v[1]); h.z = f2bf(v[2]); h.w = f2bf(v[3]);
                *reinterpret_cast<ushort4*>(
                    &Ov[(size_t)b * 2097152u + (size_t)cin * 2048 + nib]) = h;
            } else {
                unsigned short* O = z ? Ok : Oq;
#pragma unroll
                for (int r2 = 0; r2 < 4; ++r2)
                    O[(size_t)(gm + r2) * 1024 + cin] = f2bf(v[r2]);
            }
        }
    }
}

// ---------------------------------------------------------------------------
// Attention GEMMs: round 10 verbatim (passing; 2 blocks/CU desync schedule,
// MODE 2 complementary pairing).
// ---------------------------------------------------------------------------
template <int MODE>
__global__ __launch_bounds__(512, 4) void gemm_attn(
    const unsigned short* __restrict__ A0, const unsigned short* __restrict__ B0,
    float* __restrict__ Cf)
{
    __shared__ alignas(16) unsigned short lds[3 * 12288];  // slot: A 4096 + B 8192 elems

    const int tid = threadIdx.x;
    const int lane = tid & 63;
    const int wid = tid >> 6;
    const int wm = wid >> 2, wn = wid & 3;
    const int lr = lane & 15, lg = lane >> 4;

    int r128, n0, NT, bz;
    constexpr unsigned STRB = (MODE == 2) ? 2048u : 1024u;

    if constexpr (MODE == 1) {
        const int c256 = blockIdx.x;
        r128 = blockIdx.y; bz = blockIdx.z;
        if (c256 > (r128 >> 1)) return;
        n0 = c256 * 256; NT = 32;
    } else {
        const int idx = blockIdx.x;          // 512 blocks, complementary pairing
        const int k5 = idx >> 5;             // 0..15
        r128 = (k5 < 8) ? (15 - k5) : (k5 - 8);
        const int nt4 = (idx >> 3) & 3;
        bz = idx & 7;
        n0 = nt4 * 256; NT = 4 * (r128 + 1);
    }
    const int r256 = r128 >> 1;
    const unsigned short* Bb = B0 + (size_t)bz * 2097152u;

    const unsigned short* Ab;
    size_t cbase;
    if constexpr (MODE == 1) {
        Ab = A0 + (size_t)bz * 2097152u;
        cbase = ((size_t)bz * 36 + (size_t)(r256 * (r256 + 1) / 2) + (n0 >> 8)) * 65536u +
                (size_t)(r128 & 1) * 32768u;
    } else {
        Ab = A0 + ((size_t)bz * 36 + (size_t)(r256 * (r256 + 1) / 2)) * 65536u;
        cbase = (size_t)bz * 2097152u + (size_t)(r128 * 128) * 1024u;
    }

    const unsigned fswl = (unsigned)((lr ^ (lr >> 2)) & 3);
    const unsigned abase = (unsigned)(wm * 64 + lr) * 32u + ((unsigned)lg ^ fswl) * 8u;
    const unsigned bbase = 4096u + (unsigned)(wn * 32 + lr) * 32u + ((unsigned)lg ^ fswl) * 8u;

    const unsigned rowA = (unsigned)(tid >> 2);
    const unsigned chA = ((unsigned)tid & 3u) ^ (unsigned)((rowA ^ (rowA >> 2)) & 3u);
    unsigned sAoff;
    if constexpr (MODE == 1)
        sAoff = ((unsigned)(r128 * 128) + rowA) * 1024u + chA * 8u;
    else
        sAoff = ((unsigned)((r128 & 1) * 128) + rowA) * 256u + chA * 8u;
    unsigned sBoff[2];
#pragma unroll
    for (int it = 0; it < 2; ++it) {
        const unsigned idx = it * 512 + tid;
        const unsigned rowB = idx >> 2;
        const unsigned chB = (idx & 3u) ^ (unsigned)((rowB ^ (rowB >> 2)) & 3u);
        sBoff[it] = ((unsigned)n0 + rowB) * STRB + chB * 8u;
    }

#define AT_STAGE(KT, SL)                                                      \
    {                                                                         \
        unsigned u_;                                                          \
        if constexpr (MODE == 2)                                              \
            u_ = ((unsigned)((KT) >> 3)) * 65536u + ((KT) & 7) * 32u;         \
        else                                                                  \
            u_ = (unsigned)(KT) * 32u;                                        \
        gload16(Ab + u_ + sAoff, lds + (SL) * 12288 + tid * 8);               \
        gload16(Bb + (unsigned)(KT) * 32u + sBoff[0],                         \
                lds + (SL) * 12288 + 4096 + tid * 8);                         \
        gload16(Bb + (unsigned)(KT) * 32u + sBoff[1],                         \
                lds + (SL) * 12288 + 8192 + tid * 8);                         \
    }

    f32x4 acc[4][4] = {};
    bf16x8 aR[4], bv[2];

    AT_STAGE(0, 0); AT_STAGE(1, 1);

    int sl = 0, st2 = 2;
    for (int kt = 0; kt < NT; ++kt) {
        if (kt + 1 < NT) { WAITV3; } else { WAITV0; }
        BAR;
        if (kt + 2 < NT) { AT_STAGE(kt + 2, st2); }
        const unsigned short* sp = lds + sl * 12288;
#pragma unroll
        for (int fi = 0; fi < 4; ++fi)
            aR[fi] = *reinterpret_cast<const bf16x8*>(sp + abase + fi * 512);
#pragma unroll
        for (int fj = 0; fj < 2; ++fj)
            bv[fj] = *reinterpret_cast<const bf16x8*>(sp + bbase + fj * 512);
        __builtin_amdgcn_s_setprio(1);
#pragma unroll
        for (int fi = 0; fi < 4; ++fi)
#pragma unroll
            for (int fj = 0; fj < 2; ++fj)
                acc[fi][fj] = __builtin_amdgcn_mfma_f32_16x16x32_bf16(
                    aR[fi], bv[fj], acc[fi][fj], 0, 0, 0);
        __builtin_amdgcn_s_setprio(0);
#pragma unroll
        for (int fj = 0; fj < 2; ++fj)
            bv[fj] = *reinterpret_cast<const bf16x8*>(sp + bbase + 4096 + fj * 512);
        __builtin_amdgcn_s_setprio(1);
#pragma unroll
        for (int fi = 0; fi < 4; ++fi)
#pragma unroll
            for (int fj = 0; fj < 2; ++fj)
                acc[fi][2 + fj] = __builtin_amdgcn_mfma_f32_16x16x32_bf16(
                    aR[fi], bv[fj], acc[fi][2 + fj], 0, 0, 0);
        __builtin_amdgcn_s_setprio(0);
        sl = (sl == 2) ? 0 : sl + 1;
        st2 = (st2 == 2) ? 0 : st2 + 1;
    }

    // epilogue: D frag layout col=lr, row=lg*4+r2
#pragma unroll
    for (int fi = 0; fi < 4; ++fi) {
        const int rloc = wm * 64 + fi * 16 + lg * 4;
#pragma unroll
        for (int j = 0; j < 4; ++j) {
            const int cloc = (j >> 1) * 128 + wn * 32 + (j & 1) * 16 + lr;
            f32x4 v = acc[fi][j];
            if constexpr (MODE == 1) {
#pragma unroll
                for (int r2 = 0; r2 < 4; ++r2)
                    Cf[cbase + (size_t)(rloc + r2) * 256 + cloc] = v[r2];
            } else {
#pragma unroll
                for (int r2 = 0; r2 < 4; ++r2)
                    Cf[cbase + (size_t)(rloc + r2) * 1024 + (n0 + cloc)] = v[r2];
            }
        }
    }
#undef AT_STAGE
}

// ---------------------------------------------------------------------------
// row softmax over packed causal 256x256 S tiles -> packed bf16 P
// ---------------------------------------------------------------------------
__global__ __launch_bounds__(256) void softmax_rows(const float* __restrict__ Sp,
                                                    unsigned short* __restrict__ Pp) {
    const int R = blockIdx.x;
    const int b = blockIdx.y;
    const int rt = R >> 8;
    const size_t rowbase = ((size_t)b * 36 + (size_t)(rt * (rt + 1) / 2)) * 65536u +
                           (size_t)(R & 255) * 256;
    const int tid = threadIdx.x;
    const int kend = (rt + 1) << 8;

    float vals[8];
    float m = -3.0e38f;
    int cnt = 0;
    for (int k = tid; k < kend; k += 256) {
        float s = Sp[rowbase + (size_t)(k >> 8) * 65536u + (k & 255)];
        vals[cnt++] = s;
        if (k <= R) m = fmaxf(m, s);
    }
    __shared__ float red[4];
#pragma unroll
    for (int o = 32; o > 0; o >>= 1) m = fmaxf(m, __shfl_xor(m, o));
    if ((tid & 63) == 0) red[tid >> 6] = m;
    __syncthreads();
    m = fmaxf(fmaxf(red[0], red[1]), fmaxf(red[2], red[3]));
    __syncthreads();

    float l = 0.0f;
    cnt = 0;
    for (int k = tid; k < kend; k += 256) {
        float e = (k <= R) ? __expf(vals[cnt] - m) : 0.0f;
        vals[cnt] = e;
        ++cnt;
        l += e;
    }
#pragma unroll
    for (int o = 32; o > 0; o >>= 1) l += __shfl_xor(l, o);
    if ((tid & 63) == 0) red[tid >> 6] = l;
    __syncthreads();
    l = red[0] + red[1] + red[2] + red[3];
    const float inv = 1.0f / l;

    cnt = 0;
    for (int k = tid; k < kend; k += 256)
        Pp[rowbase + (size_t)(k >> 8) * 65536u + (k & 255)] = f2bf(vals[cnt++] * inv);
}

// ---------------------------------------------------------------------------
extern "C" void kernel_launch(void* const* d_in, const int* in_sizes, int n_in,
                              void* d_out, int out_size, void* d_ws, size_t ws_size,
                              hipStream_t stream) {
    const float* x  = (const float*)d_in[0];
    const float* Wq = (const float*)d_in[1];
    const float* Wk = (const float*)d_in[2];
    const float* Wv = (const float*)d_in[3];
    float* out = (float*)d_out;

    char* base = (char*)d_ws;
    unsigned short* Qb = (unsigned short*)(base);
    unsigned short* Kb = (unsigned short*)(base + 33554432u);
    unsigned short* Vt = (unsigned short*)(base + 67108864u);
    unsigned short* Xb = (unsigned short*)(base + 100663296u);
    unsigned short* Wt = (unsigned short*)(base + 134217728u);
    float*          Sp = (float*)         (base + 100663296u);   // overlays Xb/Wt
    unsigned short* Pp = (unsigned short*)(base + 176160768u);

    hipFuncSetAttribute(reinterpret_cast<const void*>(&gemm256),
                        hipFuncAttributeMaxDynamicSharedMemorySize, 98304);

    convert_x<<<16384, 256, 0, stream>>>(x, Xb);
    convert_w<<<dim3(32, 32, 3), dim3(32, 8), 0, stream>>>(Wq, Wk, Wv, Wt);
    gemm256<<<dim3(64, 12), 512, 98304, stream>>>(Xb, Wt, Qb, Kb, Vt);
    gemm_attn<1><<<dim3(8, 16, 8), 512, 0, stream>>>(Qb, Kb, Sp);
    softmax_rows<<<dim3(2048, 8), 256, 0, stream>>>(Sp, Pp);
    gemm_attn<2><<<512, 512, 0, stream>>>(Pp, Vt, out);
}

// Round 12
// 267.345 us; speedup vs baseline: 1.1101x; 1.1101x over previous
//
#include <hip/hip_runtime.h>
#include <hip/hip_bf16.h>

#define DI __device__ __forceinline__

typedef __bf16 bf16x8 __attribute__((ext_vector_type(8)));
typedef float  f32x4  __attribute__((ext_vector_type(4)));

DI unsigned short f2bf(float f) {
    unsigned int u = __float_as_uint(f);
    u += 0x7fffu + ((u >> 16) & 1u);
    return (unsigned short)(u >> 16);
}

DI void gload16(const unsigned short* g, unsigned short* l) {
    __builtin_amdgcn_global_load_lds(
        (const __attribute__((address_space(1))) unsigned int*)g,
        (__attribute__((address_space(3))) unsigned int*)l, 16, 0, 0);
}

// ---------------------------------------------------------------------------
__global__ void convert_x(const float* __restrict__ x, unsigned short* __restrict__ Xb) {
    int i = blockIdx.x * 256 + threadIdx.x;
    float4 v = reinterpret_cast<const float4*>(x)[i];
    ushort4 o;
    o.x = f2bf(v.x); o.y = f2bf(v.y); o.z = f2bf(v.z); o.w = f2bf(v.w);
    reinterpret_cast<ushort4*>(Xb)[i] = o;
}

__global__ void convert_w(const float* __restrict__ Wq, const float* __restrict__ Wk,
                          const float* __restrict__ Wv, unsigned short* __restrict__ Wt) {
    __shared__ float t[32][33];
    const int z = blockIdx.z;
    const float* W = (z == 0) ? Wq : (z == 1 ? Wk : Wv);
    const float scale = (z == 0) ? 0.03125f : 1.0f;
    const int n0 = blockIdx.x * 32, k0 = blockIdx.y * 32;
    const int tx = threadIdx.x, ty = threadIdx.y;
#pragma unroll
    for (int i = 0; i < 4; ++i)
        t[ty + i * 8][tx] = W[(size_t)(k0 + ty + i * 8) * 1024 + n0 + tx];
    __syncthreads();
#pragma unroll
    for (int i = 0; i < 4; ++i)
        Wt[(size_t)(z * 1024 + n0 + ty + i * 8) * 1024 + k0 + tx] =
            f2bf(t[tx][ty + i * 8] * scale);
}

#define BAR    asm volatile("s_barrier" ::: "memory")
#define WAITV4 asm volatile("s_waitcnt vmcnt(4)" ::: "memory")
#define WAITV3 asm volatile("s_waitcnt vmcnt(3)" ::: "memory")
#define WAITV0 asm volatile("s_waitcnt vmcnt(0)" ::: "memory")

// ---------------------------------------------------------------------------
// gemm256: ROUND-4 WINNER restored verbatim (measured 102.8-104.4 us across
// rounds 4/6/7). 256x256xBK64, 4 phases/kt, single barrier per phase,
// counted vmcnt(4) at p3, tail vmcnt(0). Best measured variant of 6 tried
// (rounds 3-11); schedule micro-variants are indistinguishable at source
// level -- do not touch without disasm evidence.
// ---------------------------------------------------------------------------

#define READ_A(SLOT, MH)                                                      \
    _Pragma("unroll")                                                         \
    for (int fi = 0; fi < 4; ++fi)                                            \
        _Pragma("unroll")                                                     \
        for (int kk = 0; kk < 2; ++kk)                                        \
            aR[fi][kk] = *reinterpret_cast<const bf16x8*>(                    \
                lsA + (SLOT) * 16384 + (MH) * 8192 +                          \
                ((abase ^ (kk * 32)) + fi * 1024));

#define READ_B(SLOT, NH, BS)                                                  \
    _Pragma("unroll")                                                         \
    for (int fj = 0; fj < 2; ++fj)                                            \
        _Pragma("unroll")                                                     \
        for (int kk = 0; kk < 2; ++kk)                                        \
            BS[fj][kk] = *reinterpret_cast<const bf16x8*>(                    \
                lsB + (SLOT) * 16384 + (NH) * 8192 +                          \
                ((bbase ^ (kk * 32)) + fj * 1024));

#define STAGE_A(KT, H)                                                        \
    {                                                                         \
        unsigned uA_ = (unsigned)(m0 + (H) * 128) * 1024u + (unsigned)(KT) * 64u; \
        _Pragma("unroll")                                                     \
        for (int it = 0; it < 2; ++it)                                        \
            gload16(Ab + uA_ + sAoff[it],                                     \
                    lsA + (((KT) & 1) * 2 + (H)) * 8192 + it * 4096 + tid * 8);\
    }

#define STAGE_B(KT, H)                                                        \
    {                                                                         \
        unsigned uB_ = (unsigned)(n0 + (H) * 128) * 1024u + (unsigned)(KT) * 64u; \
        _Pragma("unroll")                                                     \
        for (int it = 0; it < 2; ++it)                                        \
            gload16(Bb + uB_ + sBoff[it],                                     \
                    lsB + (((KT) & 1) * 2 + (H)) * 8192 + it * 4096 + tid * 8);\
    }

#define MMA_PHASE(MH, NH, BS)                                                 \
    __builtin_amdgcn_s_setprio(1);                                            \
    _Pragma("unroll")                                                         \
    for (int kk = 0; kk < 2; ++kk)                                            \
        _Pragma("unroll")                                                     \
        for (int fi = 0; fi < 4; ++fi)                                        \
            _Pragma("unroll")                                                 \
            for (int fj = 0; fj < 2; ++fj)                                    \
                acc[(MH) * 4 + fi][(NH) * 2 + fj] =                           \
                    __builtin_amdgcn_mfma_f32_16x16x32_bf16(                  \
                        aR[fi][kk], BS[fj][kk],                               \
                        acc[(MH) * 4 + fi][(NH) * 2 + fj], 0, 0, 0);          \
    __builtin_amdgcn_s_setprio(0);

__global__ __launch_bounds__(512) void gemm256(
    const unsigned short* __restrict__ A0, const unsigned short* __restrict__ B0,
    unsigned short* __restrict__ Oq, unsigned short* __restrict__ Ok,
    unsigned short* __restrict__ Ov)
{
    extern __shared__ char smem_raw[];
    unsigned short* lsA = (unsigned short*)smem_raw;
    unsigned short* lsB = lsA + 32768;

    const int tid = threadIdx.x;
    const int lane = tid & 63;
    const int wid = tid >> 6;
    const int wm = wid >> 2, wn = wid & 3;
    const int lr = lane & 15, lg = lane >> 4;

    const int m0 = blockIdx.x * 256, n0 = blockIdx.y * 256;
    const int NT = 16;
    const unsigned short* Ab = A0;
    const unsigned short* Bb = B0;

    const unsigned chm = (unsigned)(lg ^ (lr & 7));
    const unsigned abase = (unsigned)(wm * 64 + lr) * 64u + chm * 8u;
    const unsigned bbase = (unsigned)(wn * 32 + lr) * 64u + chm * 8u;
    unsigned sAoff[2], sBoff[2];
#pragma unroll
    for (int it = 0; it < 2; ++it) {
        const unsigned idx = it * 512 + tid;
        const unsigned row = idx >> 3;
        const unsigned ch = (idx & 7) ^ (row & 7);
        sAoff[it] = row * 1024u + ch * 8u;
        sBoff[it] = row * 1024u + ch * 8u;
    }

    f32x4 acc[8][4] = {};
    bf16x8 aR[4][2], b0[2][2], b1[2][2];

    STAGE_A(0, 0); STAGE_A(0, 1); STAGE_B(0, 0); STAGE_B(0, 1);
    STAGE_A(1, 0); STAGE_B(1, 0);
    WAITV4; BAR;

    for (int kt = 0; kt < NT; ++kt) {
        const int slot = kt & 1;
        const bool s1 = (kt + 1) < NT, s2 = (kt + 2) < NT;
        READ_A(slot, 0); READ_B(slot, 0, b0);
        if (s1) { STAGE_A(kt + 1, 1); }
        BAR; MMA_PHASE(0, 0, b0);
        READ_B(slot, 1, b1);
        if (s1) { STAGE_B(kt + 1, 1); }
        BAR; MMA_PHASE(0, 1, b1);
        READ_A(slot, 1);
        if (s2) { STAGE_A(kt + 2, 0); }
        BAR; MMA_PHASE(1, 0, b0);
        if (s2) {
            STAGE_B(kt + 2, 0);
            WAITV4;
        } else {
            WAITV0;
        }
        BAR; MMA_PHASE(1, 1, b1);
    }

#pragma unroll
    for (int i = 0; i < 8; ++i) {
        const int rl = (i >> 2) * 128 + wm * 64 + (i & 3) * 16 + lg * 4;
#pragma unroll
        for (int j = 0; j < 4; ++j) {
            const int cl = (j >> 1) * 128 + wn * 32 + (j & 1) * 16 + lr;
            f32x4 v = acc[i][j];
            const int gm = m0 + rl;
            const int z = n0 >> 10;
            const int cin = (n0 & 1023) + cl;
            if (z == 2) {
                const int b = gm >> 11, nib = gm & 2047;
                ushort4 h;
                h.x = f2bf(v[0]); h.y = f2bf(v[1]); h.z = f2bf(v[2]); h.w = f2bf(v[3]);
                *reinterpret_cast<ushort4*>(
                    &Ov[(size_t)b * 2097152u + (size_t)cin * 2048 + nib]) = h;
            } else {
                unsigned short* O = z ? Ok : Oq;
#pragma unroll
                for (int r2 = 0; r2 < 4; ++r2)
                    O[(size_t)(gm + r2) * 1024 + cin] = f2bf(v[r2]);
            }
        }
    }
}

// ---------------------------------------------------------------------------
// Attention GEMMs: round-8 desync structure (passing, best attn measured).
// ROUND 12 change: BOTH modes use bz-major linear grids (bz = blockIdx & 7)
// so, under round-robin blockIdx->XCD dispatch, batch k's blocks pin to XCD
// k and its Q/K (8 MB) working set stays in that XCD's L2 (T1 mechanism).
// MODE 2 keeps round-10 complementary pairing (r128 via k5 fold).
// ---------------------------------------------------------------------------
template <int MODE>
__global__ __launch_bounds__(512, 4) void gemm_attn(
    const unsigned short* __restrict__ A0, const unsigned short* __restrict__ B0,
    float* __restrict__ Cf)
{
    __shared__ alignas(16) unsigned short lds[3 * 12288];  // slot: A 4096 + B 8192 elems

    const int tid = threadIdx.x;
    const int lane = tid & 63;
    const int wid = tid >> 6;
    const int wm = wid >> 2, wn = wid & 3;
    const int lr = lane & 15, lg = lane >> 4;

    int r128, n0, NT, bz;
    constexpr unsigned STRB = (MODE == 2) ? 2048u : 1024u;

    if constexpr (MODE == 1) {
        const int idx = blockIdx.x;          // 1024 linear: bz-major for XCD pin
        bz = idx & 7;
        r128 = (idx >> 3) & 15;
        const int c256 = idx >> 7;           // 0..7
        if (c256 > (r128 >> 1)) return;
        n0 = c256 * 256; NT = 32;
    } else {
        const int idx = blockIdx.x;          // 512 blocks, complementary pairing
        const int k5 = idx >> 5;             // 0..15
        r128 = (k5 < 8) ? (15 - k5) : (k5 - 8);
        const int nt4 = (idx >> 3) & 3;
        bz = idx & 7;
        n0 = nt4 * 256; NT = 4 * (r128 + 1);
    }
    const int r256 = r128 >> 1;
    const unsigned short* Bb = B0 + (size_t)bz * 2097152u;

    const unsigned short* Ab;
    size_t cbase;
    if constexpr (MODE == 1) {
        Ab = A0 + (size_t)bz * 2097152u;
        cbase = ((size_t)bz * 36 + (size_t)(r256 * (r256 + 1) / 2) + (n0 >> 8)) * 65536u +
                (size_t)(r128 & 1) * 32768u;
    } else {
        Ab = A0 + ((size_t)bz * 36 + (size_t)(r256 * (r256 + 1) / 2)) * 65536u;
        cbase = (size_t)bz * 2097152u + (size_t)(r128 * 128) * 1024u;
    }

    const unsigned fswl = (unsigned)((lr ^ (lr >> 2)) & 3);
    const unsigned abase = (unsigned)(wm * 64 + lr) * 32u + ((unsigned)lg ^ fswl) * 8u;
    const unsigned bbase = 4096u + (unsigned)(wn * 32 + lr) * 32u + ((unsigned)lg ^ fswl) * 8u;

    const unsigned rowA = (unsigned)(tid >> 2);
    const unsigned chA = ((unsigned)tid & 3u) ^ (unsigned)((rowA ^ (rowA >> 2)) & 3u);
    unsigned sAoff;
    if constexpr (MODE == 1)
        sAoff = ((unsigned)(r128 * 128) + rowA) * 1024u + chA * 8u;
    else
        sAoff = ((unsigned)((r128 & 1) * 128) + rowA) * 256u + chA * 8u;
    unsigned sBoff[2];
#pragma unroll
    for (int it = 0; it < 2; ++it) {
        const unsigned idx = it * 512 + tid;
        const unsigned rowB = idx >> 2;
        const unsigned chB = (idx & 3u) ^ (unsigned)((rowB ^ (rowB >> 2)) & 3u);
        sBoff[it] = ((unsigned)n0 + rowB) * STRB + chB * 8u;
    }

#define AT_STAGE(KT, SL)                                                      \
    {                                                                         \
        unsigned u_;                                                          \
        if constexpr (MODE == 2)                                              \
            u_ = ((unsigned)((KT) >> 3)) * 65536u + ((KT) & 7) * 32u;         \
        else                                                                  \
            u_ = (unsigned)(KT) * 32u;                                        \
        gload16(Ab + u_ + sAoff, lds + (SL) * 12288 + tid * 8);               \
        gload16(Bb + (unsigned)(KT) * 32u + sBoff[0],                         \
                lds + (SL) * 12288 + 4096 + tid * 8);                         \
        gload16(Bb + (unsigned)(KT) * 32u + sBoff[1],                         \
                lds + (SL) * 12288 + 8192 + tid * 8);                         \
    }

    f32x4 acc[4][4] = {};
    bf16x8 aR[4], bv[2];

    AT_STAGE(0, 0); AT_STAGE(1, 1);

    int sl = 0, st2 = 2;
    for (int kt = 0; kt < NT; ++kt) {
        if (kt + 1 < NT) { WAITV3; } else { WAITV0; }
        BAR;
        if (kt + 2 < NT) { AT_STAGE(kt + 2, st2); }
        const unsigned short* sp = lds + sl * 12288;
#pragma unroll
        for (int fi = 0; fi < 4; ++fi)
            aR[fi] = *reinterpret_cast<const bf16x8*>(sp + abase + fi * 512);
#pragma unroll
        for (int fj = 0; fj < 2; ++fj)
            bv[fj] = *reinterpret_cast<const bf16x8*>(sp + bbase + fj * 512);
        __builtin_amdgcn_s_setprio(1);
#pragma unroll
        for (int fi = 0; fi < 4; ++fi)
#pragma unroll
            for (int fj = 0; fj < 2; ++fj)
                acc[fi][fj] = __builtin_amdgcn_mfma_f32_16x16x32_bf16(
                    aR[fi], bv[fj], acc[fi][fj], 0, 0, 0);
        __builtin_amdgcn_s_setprio(0);
#pragma unroll
        for (int fj = 0; fj < 2; ++fj)
            bv[fj] = *reinterpret_cast<const bf16x8*>(sp + bbase + 4096 + fj * 512);
        __builtin_amdgcn_s_setprio(1);
#pragma unroll
        for (int fi = 0; fi < 4; ++fi)
#pragma unroll
            for (int fj = 0; fj < 2; ++fj)
                acc[fi][2 + fj] = __builtin_amdgcn_mfma_f32_16x16x32_bf16(
                    aR[fi], bv[fj], acc[fi][2 + fj], 0, 0, 0);
        __builtin_amdgcn_s_setprio(0);
        sl = (sl == 2) ? 0 : sl + 1;
        st2 = (st2 == 2) ? 0 : st2 + 1;
    }

    // epilogue: D frag layout col=lr, row=lg*4+r2
#pragma unroll
    for (int fi = 0; fi < 4; ++fi) {
        const int rloc = wm * 64 + fi * 16 + lg * 4;
#pragma unroll
        for (int j = 0; j < 4; ++j) {
            const int cloc = (j >> 1) * 128 + wn * 32 + (j & 1) * 16 + lr;
            f32x4 v = acc[fi][j];
            if constexpr (MODE == 1) {
#pragma unroll
                for (int r2 = 0; r2 < 4; ++r2)
                    Cf[cbase + (size_t)(rloc + r2) * 256 + cloc] = v[r2];
            } else {
#pragma unroll
                for (int r2 = 0; r2 < 4; ++r2)
                    Cf[cbase + (size_t)(rloc + r2) * 1024 + (n0 + cloc)] = v[r2];
            }
        }
    }
#undef AT_STAGE
}

// ---------------------------------------------------------------------------
// row softmax over packed causal 256x256 S tiles -> packed bf16 P
// ---------------------------------------------------------------------------
__global__ __launch_bounds__(256) void softmax_rows(const float* __restrict__ Sp,
                                                    unsigned short* __restrict__ Pp) {
    const int R = blockIdx.x;
    const int b = blockIdx.y;
    const int rt = R >> 8;
    const size_t rowbase = ((size_t)b * 36 + (size_t)(rt * (rt + 1) / 2)) * 65536u +
                           (size_t)(R & 255) * 256;
    const int tid = threadIdx.x;
    const int kend = (rt + 1) << 8;

    float vals[8];
    float m = -3.0e38f;
    int cnt = 0;
    for (int k = tid; k < kend; k += 256) {
        float s = Sp[rowbase + (size_t)(k >> 8) * 65536u + (k & 255)];
        vals[cnt++] = s;
        if (k <= R) m = fmaxf(m, s);
    }
    __shared__ float red[4];
#pragma unroll
    for (int o = 32; o > 0; o >>= 1) m = fmaxf(m, __shfl_xor(m, o));
    if ((tid & 63) == 0) red[tid >> 6] = m;
    __syncthreads();
    m = fmaxf(fmaxf(red[0], red[1]), fmaxf(red[2], red[3]));
    __syncthreads();

    float l = 0.0f;
    cnt = 0;
    for (int k = tid; k < kend; k += 256) {
        float e = (k <= R) ? __expf(vals[cnt] - m) : 0.0f;
        vals[cnt] = e;
        ++cnt;
        l += e;
    }
#pragma unroll
    for (int o = 32; o > 0; o >>= 1) l += __shfl_xor(l, o);
    if ((tid & 63) == 0) red[tid >> 6] = l;
    __syncthreads();
    l = red[0] + red[1] + red[2] + red[3];
    const float inv = 1.0f / l;

    cnt = 0;
    for (int k = tid; k < kend; k += 256)
        Pp[rowbase + (size_t)(k >> 8) * 65536u + (k & 255)] = f2bf(vals[cnt++] * inv);
}

// ---------------------------------------------------------------------------
extern "C" void kernel_launch(void* const* d_in, const int* in_sizes, int n_in,
                              void* d_out, int out_size, void* d_ws, size_t ws_size,
                              hipStream_t stream) {
    const float* x  = (const float*)d_in[0];
    const float* Wq = (const float*)d_in[1];
    const float* Wk = (const float*)d_in[2];
    const float* Wv = (const float*)d_in[3];
    float* out = (float*)d_out;

    char* base = (char*)d_ws;
    unsigned short* Qb = (unsigned short*)(base);
    unsigned short* Kb = (unsigned short*)(base + 33554432u);
    unsigned short* Vt = (unsigned short*)(base + 67108864u);
    unsigned short* Xb = (unsigned short*)(base + 100663296u);
    unsigned short* Wt = (unsigned short*)(base + 134217728u);
    float*          Sp = (float*)         (base + 100663296u);   // overlays Xb/Wt
    unsigned short* Pp = (unsigned short*)(base + 176160768u);

    hipFuncSetAttribute(reinterpret_cast<const void*>(&gemm256),
                        hipFuncAttributeMaxDynamicSharedMemorySize, 131072);

    convert_x<<<16384, 256, 0, stream>>>(x, Xb);
    convert_w<<<dim3(32, 32, 3), dim3(32, 8), 0, stream>>>(Wq, Wk, Wv, Wt);
    gemm256<<<dim3(64, 12), 512, 131072, stream>>>(Xb, Wt, Qb, Kb, Vt);
    gemm_attn<1><<<1024, 512, 0, stream>>>(Qb, Kb, Sp);
    softmax_rows<<<dim3(2048, 8), 256, 0, stream>>>(Sp, Pp);
    gemm_attn<2><<<512, 512, 0, stream>>>(Pp, Vt, out);
}